// Round 4
// baseline (1020.488 us; speedup 1.0000x reference)
//
#include <hip/hip_runtime.h>
#include <math.h>

// SA_Layer2 — ROUND 9: k4 bank-conflict + latency fixes (round-8 green base).
// Profile r8: k4 = 430us/954us, SQ_LDS_BANK_CONFLICT 5.24e7 (~20% of cycles),
// MfmaUtil 8.2%, FETCH 354MB (ideal 80MB).
//  1) V-staging remap: old mapping had i&3 constant per wave -> all 64 lanes
//     hit the same 16B slot phase -> ~32-way ds_write_b128 conflict.  New
//     assignment: lane l covers c-group (w*16 + (l&15)), i = q*4 + (l>>4);
//     slot phase = (l>>4)*2 + (l&1): 8 lanes/phase = conflict-free minimum.
//     Read-side layout identical -> correctness-neutral.
//  2) T14 register prefetch of next iter's V chunk + Q A-frags (issued right
//     after current consumption; ~2 barriers + E + PV of latency cover).
//  3) T1 XCD swizzle on k4 (same-slice blocks on one XCD -> Vt via its L2)
//     and on gemm_proj (one batch per XCD).  Both grids % 8 == 0 (bijective).
// Everything else byte-identical to round 8.

typedef unsigned short u16;
typedef __attribute__((ext_vector_type(4))) float f32x4;
typedef __attribute__((ext_vector_type(8))) short s16x8;
typedef __attribute__((ext_vector_type(4))) short s16x4;
typedef __attribute__((ext_vector_type(4))) u16  u16x4;

__device__ __forceinline__ float b2f(u16 u) {
    unsigned x = ((unsigned)u) << 16;
    float f;
    __builtin_memcpy(&f, &x, 4);
    return f;
}
__device__ __forceinline__ u16 f2b(float f) {
    unsigned x;
    __builtin_memcpy(&x, &f, 4);
    unsigned r = (x + 0x7fffu + ((x >> 16) & 1u)) >> 16;  // round-nearest-even
    return (u16)r;
}
__device__ __forceinline__ float expc(float e) {
    return expf(fminf(e, 80.0f));
}

// ---------------------------------------------------------------------------
// MFMA projection GEMM.  grid = 1D (XCD-swizzled), block = 256.
// ---------------------------------------------------------------------------
template<int MODE>
__global__ __launch_bounds__(256) void gemm_proj(
    const float* __restrict__ W, const float* __restrict__ bias,
    const float* __restrict__ x, const u16* __restrict__ XR,
    u16* __restrict__ outb, float* __restrict__ outf)
{
    constexpr int MY = (MODE == 0) ? 1 : 4;
    const int nwg  = 64 * MY * 8;
    const int orig = blockIdx.x;
    const int swz  = (orig & 7) * (nwg >> 3) + (orig >> 3);
    const int b    = swz / (64 * MY);
    const int rem  = swz - b * 64 * MY;
    const int n0   = (rem & 63) * 128;
    const int m0   = (rem >> 6) * 128;

    const int tid  = threadIdx.x;
    const int wv   = tid >> 6;
    const int lane = tid & 63;
    const int lr   = lane & 15;
    const int lg   = lane >> 4;
    const int wm   = (wv & 1) * 64;
    const int wn   = (wv >> 1) * 64;

    __shared__ __align__(16) short lA[128 * 64];
    __shared__ __align__(16) short lB[128 * 64];

    f32x4 acc[4][4];
    const f32x4 zero = {0.f, 0.f, 0.f, 0.f};
#pragma unroll
    for (int i = 0; i < 4; ++i)
#pragma unroll
        for (int j = 0; j < 4; ++j) acc[i][j] = zero;

    const int am   = tid >> 3;
    const int akg  = tid & 7;
    const int xn   = tid & 127;
    const int xkgb = (tid >> 7) * 4;

    s16x8 aS[4], xS[4];

    auto loadstep = [&](int ks) {
        const int k0 = ks * 64;
#pragma unroll
        for (int q = 0; q < 4; ++q) {
            const int m = am + q * 32;
            const float* src = W + (size_t)(m0 + m) * 512 + k0 + akg * 8;
            f32x4 u0 = *(const f32x4*)src;
            f32x4 u1 = *(const f32x4*)(src + 4);
            s16x8 r;
#pragma unroll
            for (int j = 0; j < 4; ++j) {
                r[j]     = (short)f2b(u0[j]);
                r[4 + j] = (short)f2b(u1[j]);
            }
            aS[q] = r;
        }
#pragma unroll
        for (int q = 0; q < 4; ++q) {
            const int kg = xkgb + q;
            s16x8 r;
#pragma unroll
            for (int j = 0; j < 8; ++j) {
                const int k = k0 + kg * 8 + j;
                const size_t idx = ((size_t)(b * 512 + k)) * 8192 + n0 + xn;
                float v = x[idx];
                if (MODE == 2) v -= b2f(XR[idx]);
                r[j] = (short)f2b(v);
            }
            xS[q] = r;
        }
    };

    auto writestep = [&]() {
#pragma unroll
        for (int q = 0; q < 4; ++q) {
            const int m = am + q * 32;
            *(s16x8*)(lA + m * 64 + ((akg ^ (m & 7)) << 3)) = aS[q];
        }
#pragma unroll
        for (int q = 0; q < 4; ++q) {
            const int kg = xkgb + q;
            *(s16x8*)(lB + xn * 64 + ((kg ^ (xn & 7)) << 3)) = xS[q];
        }
    };

    loadstep(0);
    for (int ks = 0; ks < 8; ++ks) {
        __syncthreads();
        writestep();
        __syncthreads();
        if (ks < 7) loadstep(ks + 1);
#pragma unroll
        for (int kk = 0; kk < 2; ++kk) {
            const int g = kk * 4 + lg;
            s16x8 af[4], bf[4];
#pragma unroll
            for (int f = 0; f < 4; ++f) {
                const int r = wm + f * 16 + lr;
                af[f] = *(const s16x8*)(lA + r * 64 + ((g ^ (r & 7)) << 3));
            }
#pragma unroll
            for (int f = 0; f < 4; ++f) {
                const int r = wn + f * 16 + lr;
                bf[f] = *(const s16x8*)(lB + r * 64 + ((g ^ (r & 7)) << 3));
            }
#pragma unroll
            for (int fm = 0; fm < 4; ++fm)
#pragma unroll
                for (int fn = 0; fn < 4; ++fn)
                    acc[fm][fn] = __builtin_amdgcn_mfma_f32_16x16x32_bf16(
                        af[fm], bf[fn], acc[fm][fn], 0, 0, 0);
        }
    }

#pragma unroll
    for (int fm = 0; fm < 4; ++fm) {
        const int m = m0 + wm + fm * 16 + lg * 4;
#pragma unroll
        for (int fn = 0; fn < 4; ++fn) {
            const int n = n0 + wn + fn * 16 + lr;
            if (MODE == 0) {
                const size_t base =
                    ((size_t)((b * 8 + (n & 7)) * 1024 + (n >> 3))) * 128 + m;
                u16x4 o;
#pragma unroll
                for (int r = 0; r < 4; ++r) o[r] = f2b(acc[fm][fn][r]);
                *(u16x4*)(outb + base) = o;
            } else if (MODE == 1) {
                const size_t base =
                    ((size_t)((b * 8 + (n & 7)) * 1024 + (n >> 3))) * 512 + m;
                u16x4 o;
#pragma unroll
                for (int r = 0; r < 4; ++r)
                    o[r] = f2b(acc[fm][fn][r] + bias[m + r]);
                *(u16x4*)(outb + base) = o;
            } else {
#pragma unroll
                for (int r = 0; r < 4; ++r)
                    outf[((size_t)(b * 512 + m + r)) * 8192 + n] =
                        acc[fm][fn][r] + bias[m + r];
            }
        }
    }
}

// ---------------------------------------------------------------------------
// k4_fused: attention (E, exp, colsum, PV, normalize) all-MFMA.
// grid = 2048 (XCD-swizzled), block = 256 (4 waves).
// ---------------------------------------------------------------------------
__global__ __launch_bounds__(256) void k4_fused(
    const u16* __restrict__ Qs, const u16* __restrict__ Vt, u16* __restrict__ XR)
{
    const int orig = blockIdx.x;
    const int swz  = (orig & 7) * 256 + (orig >> 3);   // nwg=2048, bijective
    const int s    = swz >> 5;         // 0..63  (8 slices per XCD)
    const int jt   = swz & 31;         // 0..31

    const int tid  = threadIdx.x;
    const int b    = s >> 3, wimg = s & 7;
    const int j0   = jt * 32;
    const int w    = tid >> 6;
    const int lane = tid & 63;
    const int l15  = lane & 15;
    const int lg   = lane >> 4;
    const int jsub = w & 1;
    const int ih   = w >> 1;           // E: i-sub;  PV: c-half

    __shared__ __align__(128) short Vl[32 * 512];   // [cg32][ig8][4][16]
    __shared__ __align__(128) short Pl[2 * 8 * 64]; // [jg2][ig8][4][16]
    __shared__ float csum_lds[2][32];
    __shared__ float rls_lds[32];

    const unsigned vbase = (unsigned)(uintptr_t)(void*)Vl;
    const unsigned pbase = (unsigned)(uintptr_t)(void*)Pl;
    const long qrow = (long)s * 1024;

    // preload Q_j B-frags (wave's 16 j rows, K=128)
    s16x8 qj[4];
    {
        const int j = j0 + jsub * 16 + l15;
#pragma unroll
        for (int kk = 0; kk < 4; ++kk)
            qj[kk] = *(const s16x8*)(Qs + (qrow + j) * 128 + (kk * 4 + lg) * 8);
    }

    f32x4 acc[16];
    const f32x4 zero = {0.f, 0.f, 0.f, 0.f};
#pragma unroll
    for (int f = 0; f < 16; ++f) acc[f] = zero;
    float csum = 0.f;

    const unsigned lanebyte = (unsigned)(lane * 8);   // tr-read lane offset

    // ---- conflict-free V staging assignment ----
    // lane covers c-group scg = w*16 + (l&15) (8 ch), i = q*4 + (l>>4).
    // LDS slot phase = (l>>4)*2 + (l&1): 8 lanes per 16B phase (free).
    const int scg = w * 16 + l15;          // 0..63
    const int sc0 = scg * 8;
    const int sio = lg;                    // i offset in quad (0..3)
    const unsigned vsub = (unsigned)((scg >> 1) * 8);
    const unsigned voff = (unsigned)((scg & 1) * 8);

    s16x8 vS[8];
    s16x8 qS[4];

    auto vload = [&](int it2) {
        const int ib = it2 * 32 + sio;
#pragma unroll
        for (int q = 0; q < 8; ++q)
            vS[q] = *(const s16x8*)(Vt + (qrow + ib + q * 4) * 512 + sc0);
    };
    auto qload = [&](int it2) {
        const int irow = it2 * 32 + ih * 16 + l15;
#pragma unroll
        for (int kk = 0; kk < 4; ++kk)
            qS[kk] = *(const s16x8*)(Qs + (qrow + irow) * 128 + (kk * 4 + lg) * 8);
    };

    vload(0);
    qload(0);

    for (int it = 0; it < 32; ++it) {
        __syncthreads();   // prev PV done reading Vl & Pl

        // ---- write staged V regs -> Vl (conflict-free b128) ----
#pragma unroll
        for (int q = 0; q < 8; ++q)
            *(s16x8*)(Vl + (vsub + (unsigned)q) * 64 + sio * 16 + voff) = vS[q];

        // ---- prefetch next V chunk (in flight across E + PV) ----
        if (it < 31) vload(it + 1);

        // ---- E phase: 16x16 tile (qS consumed), exp, colsum, P write ----
        f32x4 e = zero;
#pragma unroll
        for (int kk = 0; kk < 4; ++kk)
            e = __builtin_amdgcn_mfma_f32_16x16x32_bf16(qS[kk], qj[kk], e, 0, 0, 0);

        // ---- prefetch next Q A-frags (qS free now) ----
        if (it < 31) qload(it + 1);

#pragma unroll
        for (int r = 0; r < 4; ++r) {
            const float pe = expc(e[r]);
            csum += pe;
            const int il = ih * 16 + 4 * lg + r;         // local i (0..31)
            Pl[(jsub * 8 + (il >> 2)) * 64 + (il & 3) * 16 + l15] =
                (short)f2b(pe);
        }
        __syncthreads();   // Vl + Pl visible

        // ---- PV phase: tr-reads + MFMAs, 4-frag batches, counted waits ----
        {
            const unsigned abase = pbase + (unsigned)(jsub * 1024) + lanebyte;
            s16x4 pa0, pa1;
            asm volatile("ds_read_b64_tr_b16 %0, %1" : "=v"(pa0) : "v"(abase));
            asm volatile("ds_read_b64_tr_b16 %0, %1" : "=v"(pa1) : "v"(abase + 512u));
            const unsigned bstart = vbase + (unsigned)(ih * 16384) + lanebyte;
            s16x4 bb[2][4][2];
#pragma unroll
            for (int f = 0; f < 4; ++f) {
                const unsigned ba = bstart + (unsigned)(f * 1024);
                asm volatile("ds_read_b64_tr_b16 %0, %1" : "=v"(bb[0][f][0]) : "v"(ba));
                asm volatile("ds_read_b64_tr_b16 %0, %1" : "=v"(bb[0][f][1]) : "v"(ba + 512u));
            }
            s16x8 af;
#pragma unroll
            for (int bt = 0; bt < 4; ++bt) {
                if (bt < 3) {
#pragma unroll
                    for (int f = 0; f < 4; ++f) {
                        const unsigned ba =
                            bstart + (unsigned)(((bt + 1) * 4 + f) * 1024);
                        asm volatile("ds_read_b64_tr_b16 %0, %1"
                                     : "=v"(bb[(bt + 1) & 1][f][0]) : "v"(ba));
                        asm volatile("ds_read_b64_tr_b16 %0, %1"
                                     : "=v"(bb[(bt + 1) & 1][f][1]) : "v"(ba + 512u));
                    }
                    asm volatile("s_waitcnt lgkmcnt(8)");
                } else {
                    asm volatile("s_waitcnt lgkmcnt(0)");
                }
                __builtin_amdgcn_sched_barrier(0);
                if (bt == 0) {
#pragma unroll
                    for (int j = 0; j < 4; ++j) { af[j] = pa0[j]; af[4 + j] = pa1[j]; }
                }
#pragma unroll
                for (int f = 0; f < 4; ++f) {
                    s16x8 bf;
#pragma unroll
                    for (int j = 0; j < 4; ++j) {
                        bf[j]     = bb[bt & 1][f][0][j];
                        bf[4 + j] = bb[bt & 1][f][1][j];
                    }
                    acc[bt * 4 + f] = __builtin_amdgcn_mfma_f32_16x16x32_bf16(
                        af, bf, acc[bt * 4 + f], 0, 0, 0);
                }
            }
        }
    }

    // ---- colsum reduce -> rls ----
    __syncthreads();
    csum += __shfl_xor(csum, 16, 64);
    csum += __shfl_xor(csum, 32, 64);
    if (lane < 16) csum_lds[ih][jsub * 16 + lane] = csum;
    __syncthreads();
    if (tid < 32)
        rls_lds[tid] = 1.0f / ((1.0f + 1e-9f) * (csum_lds[0][tid] + csum_lds[1][tid]));
    __syncthreads();

    // ---- epilogue: scale by rls[j], store XR (x-layout) ----
#pragma unroll
    for (int f = 0; f < 16; ++f) {
        const int c = ih * 256 + f * 16 + l15;
        u16* dst = XR + ((size_t)(b * 512 + c)) * 8192;
#pragma unroll
        for (int r = 0; r < 4; ++r) {
            const int jl = jsub * 16 + 4 * lg + r;
            dst[(j0 + jl) * 8 + wimg] = f2b(acc[f][r] * rls_lds[jl]);
        }
    }
}

// ---------------------------------------------------------------------------
// K6: one block per channel; float4 loads; deterministic LDS reduction.
// ---------------------------------------------------------------------------
__global__ __launch_bounds__(256) void k6_bnstats(
    const float* T, const float* gamma, const float* beta, float* bnp)
{
    const int c   = blockIdx.x;
    const int tid = threadIdx.x;
    float s1 = 0.f, s2 = 0.f;
    for (int b = 0; b < 8; ++b) {
        const f32x4* p = (const f32x4*)(T + ((long)(b * 512 + c)) * 8192);
        for (int m = 0; m < 8; ++m) {
            const f32x4 f = p[m * 256 + tid];
#pragma unroll
            for (int j = 0; j < 4; ++j) { s1 += f[j]; s2 += f[j] * f[j]; }
        }
    }
    __shared__ float r1[256], r2[256];
    r1[tid] = s1; r2[tid] = s2;
    __syncthreads();
    for (int o = 128; o > 0; o >>= 1) {
        if (tid < o) { r1[tid] += r1[tid + o]; r2[tid] += r2[tid + o]; }
        __syncthreads();
    }
    if (tid == 0) {
        const float inv_n = 1.0f / 65536.0f;
        const float mean = r1[0] * inv_n;
        const float var  = r2[0] * inv_n - mean * mean;
        const float sc   = gamma[c] * rsqrtf(var + 1e-5f);
        bnp[c]       = sc;
        bnp[512 + c] = beta[c] - mean * sc;
    }
}

// ---------------------------------------------------------------------------
// K7: out = x + relu(T*scale + shift), in place, float4 vectorized.
// ---------------------------------------------------------------------------
__global__ __launch_bounds__(256) void k7_final(
    const float* x, const float* bnp, float* out)
{
    const long i = ((long)blockIdx.x * 256 + threadIdx.x) * 4;
    const int c = (int)((i >> 13) & 511);
    const float sc = bnp[c], sh = bnp[512 + c];
    f32x4 t  = *(const f32x4*)(out + i);
    f32x4 xv = *(const f32x4*)(x + i);
    f32x4 r;
#pragma unroll
    for (int j = 0; j < 4; ++j) {
        float v = t[j] * sc + sh;
        if (v < 0.f) v = 0.f;
        r[j] = xv[j] + v;
    }
    *(f32x4*)(out + i) = r;
}

extern "C" void kernel_launch(void* const* d_in, const int* in_sizes, int n_in,
                              void* d_out, int out_size, void* d_ws, size_t ws_size,
                              hipStream_t stream)
{
    const float* x     = (const float*)d_in[0];
    const float* qk_w  = (const float*)d_in[1];
    const float* v_w   = (const float*)d_in[2];
    const float* v_b   = (const float*)d_in[3];
    const float* t_w   = (const float*)d_in[4];
    const float* t_b   = (const float*)d_in[5];
    const float* gamma = (const float*)d_in[6];
    const float* beta  = (const float*)d_in[7];
    float* out = (float*)d_out;

    char* ws = (char*)d_ws;
    u16*   Qs   = (u16*)(ws);                    // 16 MiB  [64][1024][128]
    u16*   Vt   = (u16*)(ws + 16777216);         // 64 MiB  [64][1024][512]
    u16*   XR   = (u16*)(ws + 83886080);         // 64 MiB  x-layout
    float* bnp  = (float*)(ws + 151257088);      // 4 KiB
    // ws layout unchanged (lbuf slot unused)

    gemm_proj<0><<<dim3(512),  256, 0, stream>>>(
        qk_w, nullptr, x, nullptr, Qs, nullptr);
    gemm_proj<1><<<dim3(2048), 256, 0, stream>>>(
        v_w, v_b, x, nullptr, Vt, nullptr);
    k4_fused <<<dim3(2048), 256, 0, stream>>>(Qs, Vt, XR);
    gemm_proj<2><<<dim3(2048), 256, 0, stream>>>(
        t_w, t_b, x, XR, nullptr, out);
    k6_bnstats <<<dim3(512),  256, 0, stream>>>(out, gamma, beta, bnp);
    k7_final <<<dim3(33554432 / 1024), 256, 0, stream>>>(x, bnp, out);
}

// Round 5
// 991.258 us; speedup vs baseline: 1.0295x; 1.0295x over previous
//
#include <hip/hip_runtime.h>
#include <math.h>

// SA_Layer2 — ROUND 10: remove tr-reads from k4 (they ARE the bank conflicts:
// SQ_LDS_BANK_CONFLICT identical 5.243e7 across r8/r9 though ds_writes changed;
// m217: tr_read conflicts are HW-transpose-specific).  New k4 PV:
//   - P stored TRANSPOSED at source: lane holds E[i=4lg+r][j=l15], r-consec =
//     i-consec -> one b64 write to Pt[j][i].  A-frag = plain ds_read_b128.
//   - Vt global layout changed to [s][c][i] (gemm MODE1 epilogue pays scalar
//     stores) -> V stages to Vl[c][i] via b128 global reads + b128 LDS writes;
//     PV B-frag = plain ds_read_b128.
//   - rows padded to 40 u16 (80B stride: 16B-aligned b128, row*20%32 spreads
//     uniformly over bank groups -> 8-deep = conflict-free minimum).
// XR global layout -> [s][h][c]: k4 epilogue 32B-coalesced (fixes r9's 528MB
// write amplification while KEEPING k4 XCD swizzle / 50MB FETCH), MODE2 reads
// XR as one b128 per lane.  gemm grids reverted to r8 form (measured faster).

typedef unsigned short u16;
typedef __attribute__((ext_vector_type(4))) float f32x4;
typedef __attribute__((ext_vector_type(8))) short s16x8;
typedef __attribute__((ext_vector_type(4))) u16  u16x4;

__device__ __forceinline__ float b2f(u16 u) {
    unsigned x = ((unsigned)u) << 16;
    float f;
    __builtin_memcpy(&f, &x, 4);
    return f;
}
__device__ __forceinline__ u16 f2b(float f) {
    unsigned x;
    __builtin_memcpy(&x, &f, 4);
    unsigned r = (x + 0x7fffu + ((x >> 16) & 1u)) >> 16;  // round-nearest-even
    return (u16)r;
}
__device__ __forceinline__ float expc(float e) {
    return expf(fminf(e, 80.0f));
}

// ---------------------------------------------------------------------------
// MFMA projection GEMM.  grid = (64, M/128, 8), block = 256.
//  MODE 0: Qs [s][h][128]   (bf16)
//  MODE 1: Vt [s][c][1024]  (bf16)  <-- layout changed this round
//  MODE 2: T  fp32 x-layout; input = x - XR, XR read from [s][h][c]
// ---------------------------------------------------------------------------
template<int MODE>
__global__ __launch_bounds__(256) void gemm_proj(
    const float* __restrict__ W, const float* __restrict__ bias,
    const float* __restrict__ x, const u16* __restrict__ XR,
    u16* __restrict__ outb, float* __restrict__ outf)
{
    const int tid  = threadIdx.x;
    const int b    = blockIdx.z;
    const int n0   = blockIdx.x * 128;
    const int m0   = blockIdx.y * 128;
    const int wv   = tid >> 6;
    const int lane = tid & 63;
    const int lr   = lane & 15;
    const int lg   = lane >> 4;
    const int wm   = (wv & 1) * 64;
    const int wn   = (wv >> 1) * 64;

    __shared__ __align__(16) short lA[128 * 64];
    __shared__ __align__(16) short lB[128 * 64];

    f32x4 acc[4][4];
    const f32x4 zero = {0.f, 0.f, 0.f, 0.f};
#pragma unroll
    for (int i = 0; i < 4; ++i)
#pragma unroll
        for (int j = 0; j < 4; ++j) acc[i][j] = zero;

    const int am   = tid >> 3;
    const int akg  = tid & 7;
    const int xn   = tid & 127;
    const int xkgb = (tid >> 7) * 4;

    s16x8 aS[4], xS[4];

    auto loadstep = [&](int ks) {
        const int k0 = ks * 64;
#pragma unroll
        for (int q = 0; q < 4; ++q) {
            const int m = am + q * 32;
            const float* src = W + (size_t)(m0 + m) * 512 + k0 + akg * 8;
            f32x4 u0 = *(const f32x4*)src;
            f32x4 u1 = *(const f32x4*)(src + 4);
            s16x8 r;
#pragma unroll
            for (int j = 0; j < 4; ++j) {
                r[j]     = (short)f2b(u0[j]);
                r[4 + j] = (short)f2b(u1[j]);
            }
            aS[q] = r;
        }
        const int hw = n0 + xn;
#pragma unroll
        for (int q = 0; q < 4; ++q) {
            const int kg = xkgb + q;
            s16x8 r;
            s16x8 xr8;
            if (MODE == 2)
                xr8 = *(const s16x8*)(XR +
                    ((size_t)((b * 8 + (hw & 7)) * 1024 + (hw >> 3))) * 512 +
                    k0 + kg * 8);
#pragma unroll
            for (int j = 0; j < 8; ++j) {
                const int k = k0 + kg * 8 + j;
                float v = x[((size_t)(b * 512 + k)) * 8192 + hw];
                if (MODE == 2) v -= b2f((u16)xr8[j]);
                r[j] = (short)f2b(v);
            }
            xS[q] = r;
        }
    };

    auto writestep = [&]() {
#pragma unroll
        for (int q = 0; q < 4; ++q) {
            const int m = am + q * 32;
            *(s16x8*)(lA + m * 64 + ((akg ^ (m & 7)) << 3)) = aS[q];
        }
#pragma unroll
        for (int q = 0; q < 4; ++q) {
            const int kg = xkgb + q;
            *(s16x8*)(lB + xn * 64 + ((kg ^ (xn & 7)) << 3)) = xS[q];
        }
    };

    loadstep(0);
    for (int ks = 0; ks < 8; ++ks) {
        __syncthreads();
        writestep();
        __syncthreads();
        if (ks < 7) loadstep(ks + 1);
#pragma unroll
        for (int kk = 0; kk < 2; ++kk) {
            const int g = kk * 4 + lg;
            s16x8 af[4], bf[4];
#pragma unroll
            for (int f = 0; f < 4; ++f) {
                const int r = wm + f * 16 + lr;
                af[f] = *(const s16x8*)(lA + r * 64 + ((g ^ (r & 7)) << 3));
            }
#pragma unroll
            for (int f = 0; f < 4; ++f) {
                const int r = wn + f * 16 + lr;
                bf[f] = *(const s16x8*)(lB + r * 64 + ((g ^ (r & 7)) << 3));
            }
#pragma unroll
            for (int fm = 0; fm < 4; ++fm)
#pragma unroll
                for (int fn = 0; fn < 4; ++fn)
                    acc[fm][fn] = __builtin_amdgcn_mfma_f32_16x16x32_bf16(
                        af[fm], bf[fn], acc[fm][fn], 0, 0, 0);
        }
    }

#pragma unroll
    for (int fm = 0; fm < 4; ++fm) {
        const int m = m0 + wm + fm * 16 + lg * 4;
#pragma unroll
        for (int fn = 0; fn < 4; ++fn) {
            const int n = n0 + wn + fn * 16 + lr;
            if (MODE == 0) {
                const size_t base =
                    ((size_t)((b * 8 + (n & 7)) * 1024 + (n >> 3))) * 128 + m;
                u16x4 o;
#pragma unroll
                for (int r = 0; r < 4; ++r) o[r] = f2b(acc[fm][fn][r]);
                *(u16x4*)(outb + base) = o;
            } else if (MODE == 1) {
                // Vt [s][c][h]: c = m+r, h = n>>3, s = b*8 + (n&7)
                const size_t base =
                    ((size_t)((b * 8 + (n & 7)) * 512 + m)) * 1024 + (n >> 3);
#pragma unroll
                for (int r = 0; r < 4; ++r)
                    outb[base + (size_t)r * 1024] =
                        f2b(acc[fm][fn][r] + bias[m + r]);
            } else {
#pragma unroll
                for (int r = 0; r < 4; ++r)
                    outf[((size_t)(b * 512 + m + r)) * 8192 + n] =
                        acc[fm][fn][r] + bias[m + r];
            }
        }
    }
}

// ---------------------------------------------------------------------------
// k4_fused: attention, all-MFMA, no tr-reads.
// grid = 2048 (XCD-swizzled), block = 256 (4 waves).
// wave (jsub = w&1, ih = w>>1): E quadrant (i-half ih, j-half jsub);
// PV: D[j(16, jsub), c(256, ih)] accumulated over i.
// ---------------------------------------------------------------------------
__global__ __launch_bounds__(256) void k4_fused(
    const u16* __restrict__ Qs, const u16* __restrict__ Vt, u16* __restrict__ XR)
{
    const int orig = blockIdx.x;
    const int swz  = (orig & 7) * 256 + (orig >> 3);   // nwg=2048, bijective
    const int s    = swz >> 5;
    const int jt   = swz & 31;

    const int tid  = threadIdx.x;
    const int j0   = jt * 32;
    const int w    = tid >> 6;
    const int lane = tid & 63;
    const int l15  = lane & 15;
    const int lg   = lane >> 4;
    const int jsub = w & 1;
    const int ih   = w >> 1;

    // padded rows: 32 i + 8 pad = 40 u16 (80 B = 16B-aligned stride;
    // row*20 mod 32 spreads b128 starts uniformly -> 8-deep, conflict-free)
    __shared__ __align__(16) short Vl[512 * 40];   // [c][i]
    __shared__ __align__(16) short Pt[32 * 40];    // [j][i]
    __shared__ float csum_lds[2][32];
    __shared__ float rls_lds[32];

    const long qrow = (long)s * 1024;
    const u16* vslice = Vt + (size_t)s * 512 * 1024;

    // preload Q_j B-frags (wave's 16 j rows, K=128)
    s16x8 qj[4];
    {
        const int j = j0 + jsub * 16 + l15;
#pragma unroll
        for (int kk = 0; kk < 4; ++kk)
            qj[kk] = *(const s16x8*)(Qs + (qrow + j) * 128 + (kk * 4 + lg) * 8);
    }

    f32x4 acc[16];
    const f32x4 zero = {0.f, 0.f, 0.f, 0.f};
#pragma unroll
    for (int f = 0; f < 16; ++f) acc[f] = zero;
    float csum = 0.f;

    // V staging: lane covers c = (tid>>2) + q*64, i-granule = tid&3
    const int sc  = tid >> 2;
    const int sig = tid & 3;

    s16x8 vS[8], qS[4];

    auto vload = [&](int it2) {
        const int ib = it2 * 32 + sig * 8;
#pragma unroll
        for (int q = 0; q < 8; ++q)
            vS[q] = *(const s16x8*)(vslice + (size_t)(sc + q * 64) * 1024 + ib);
    };
    auto qload = [&](int it2) {
        const int irow = it2 * 32 + ih * 16 + l15;
#pragma unroll
        for (int kk = 0; kk < 4; ++kk)
            qS[kk] = *(const s16x8*)(Qs + (qrow + irow) * 128 + (kk * 4 + lg) * 8);
    };

    vload(0);
    qload(0);

    for (int it = 0; it < 32; ++it) {
        __syncthreads();   // prev PV done reading Vl & Pt

        // ---- staged V regs -> Vl[c][i] (b128, uniform bank spread) ----
#pragma unroll
        for (int q = 0; q < 8; ++q)
            *(s16x8*)(Vl + (sc + q * 64) * 40 + sig * 8) = vS[q];
        if (it < 31) vload(it + 1);

        // ---- E phase: 16x16 quadrant via MFMA ----
        f32x4 e = zero;
#pragma unroll
        for (int kk = 0; kk < 4; ++kk)
            e = __builtin_amdgcn_mfma_f32_16x16x32_bf16(qS[kk], qj[kk], e, 0, 0, 0);
        if (it < 31) qload(it + 1);

        // exp, colsum, transposed P store: lane has E[i=ih*16+4lg+r][j=l15],
        // r-consecutive = i-consecutive -> one b64 to Pt[j][i]
        u16x4 p4;
#pragma unroll
        for (int r = 0; r < 4; ++r) {
            const float pe = expc(e[r]);
            csum += pe;
            p4[r] = f2b(pe);
        }
        *(u16x4*)(Pt + (jsub * 16 + l15) * 40 + ih * 16 + lg * 4) = p4;

        __syncthreads();   // Vl + Pt visible

        // ---- PV: plain b128 frag reads + 16 MFMAs ----
        const s16x8 af = *(const s16x8*)(Pt + (jsub * 16 + l15) * 40 + lg * 8);
#pragma unroll
        for (int fc = 0; fc < 16; ++fc) {
            const s16x8 bf =
                *(const s16x8*)(Vl + (ih * 256 + fc * 16 + l15) * 40 + lg * 8);
            acc[fc] = __builtin_amdgcn_mfma_f32_16x16x32_bf16(
                af, bf, acc[fc], 0, 0, 0);
        }
    }

    // ---- colsum reduce -> rls ----
    __syncthreads();
    csum += __shfl_xor(csum, 16, 64);
    csum += __shfl_xor(csum, 32, 64);
    if (lane < 16) csum_lds[ih][jsub * 16 + lane] = csum;
    __syncthreads();
    if (tid < 32)
        rls_lds[tid] = 1.0f / ((1.0f + 1e-9f) * (csum_lds[0][tid] + csum_lds[1][tid]));
    __syncthreads();

    // ---- epilogue: XR [s][h][c]; lanes l15 -> 32B-coalesced segments ----
    u16* xslice = XR + (size_t)s * 512 * 1024;
#pragma unroll
    for (int f = 0; f < 16; ++f) {
        const int c = ih * 256 + f * 16 + l15;
#pragma unroll
        for (int r = 0; r < 4; ++r) {
            const int jl = jsub * 16 + 4 * lg + r;
            xslice[(size_t)(j0 + jl) * 512 + c] = f2b(acc[f][r] * rls_lds[jl]);
        }
    }
}

// ---------------------------------------------------------------------------
// K6: one block per channel; float4 loads; deterministic LDS reduction.
// ---------------------------------------------------------------------------
__global__ __launch_bounds__(256) void k6_bnstats(
    const float* T, const float* gamma, const float* beta, float* bnp)
{
    const int c   = blockIdx.x;
    const int tid = threadIdx.x;
    float s1 = 0.f, s2 = 0.f;
    for (int b = 0; b < 8; ++b) {
        const f32x4* p = (const f32x4*)(T + ((long)(b * 512 + c)) * 8192);
        for (int m = 0; m < 8; ++m) {
            const f32x4 f = p[m * 256 + tid];
#pragma unroll
            for (int j = 0; j < 4; ++j) { s1 += f[j]; s2 += f[j] * f[j]; }
        }
    }
    __shared__ float r1[256], r2[256];
    r1[tid] = s1; r2[tid] = s2;
    __syncthreads();
    for (int o = 128; o > 0; o >>= 1) {
        if (tid < o) { r1[tid] += r1[tid + o]; r2[tid] += r2[tid + o]; }
        __syncthreads();
    }
    if (tid == 0) {
        const float inv_n = 1.0f / 65536.0f;
        const float mean = r1[0] * inv_n;
        const float var  = r2[0] * inv_n - mean * mean;
        const float sc   = gamma[c] * rsqrtf(var + 1e-5f);
        bnp[c]       = sc;
        bnp[512 + c] = beta[c] - mean * sc;
    }
}

// ---------------------------------------------------------------------------
// K7: out = x + relu(T*scale + shift), in place, float4 vectorized.
// ---------------------------------------------------------------------------
__global__ __launch_bounds__(256) void k7_final(
    const float* x, const float* bnp, float* out)
{
    const long i = ((long)blockIdx.x * 256 + threadIdx.x) * 4;
    const int c = (int)((i >> 13) & 511);
    const float sc = bnp[c], sh = bnp[512 + c];
    f32x4 t  = *(const f32x4*)(out + i);
    f32x4 xv = *(const f32x4*)(x + i);
    f32x4 r;
#pragma unroll
    for (int j = 0; j < 4; ++j) {
        float v = t[j] * sc + sh;
        if (v < 0.f) v = 0.f;
        r[j] = xv[j] + v;
    }
    *(f32x4*)(out + i) = r;
}

extern "C" void kernel_launch(void* const* d_in, const int* in_sizes, int n_in,
                              void* d_out, int out_size, void* d_ws, size_t ws_size,
                              hipStream_t stream)
{
    const float* x     = (const float*)d_in[0];
    const float* qk_w  = (const float*)d_in[1];
    const float* v_w   = (const float*)d_in[2];
    const float* v_b   = (const float*)d_in[3];
    const float* t_w   = (const float*)d_in[4];
    const float* t_b   = (const float*)d_in[5];
    const float* gamma = (const float*)d_in[6];
    const float* beta  = (const float*)d_in[7];
    float* out = (float*)d_out;

    char* ws = (char*)d_ws;
    u16*   Qs   = (u16*)(ws);                    // 16 MiB  [64][1024][128]
    u16*   Vt   = (u16*)(ws + 16777216);         // 64 MiB  [64][512][1024]  (c-major)
    u16*   XR   = (u16*)(ws + 83886080);         // 64 MiB  [64][1024][512]  (h-major)
    float* bnp  = (float*)(ws + 151257088);      // 4 KiB
    // ws layout/offsets unchanged

    gemm_proj<0><<<dim3(64, 1, 8), 256, 0, stream>>>(
        qk_w, nullptr, x, nullptr, Qs, nullptr);
    gemm_proj<1><<<dim3(64, 4, 8), 256, 0, stream>>>(
        v_w, v_b, x, nullptr, Vt, nullptr);
    k4_fused <<<dim3(2048), 256, 0, stream>>>(Qs, Vt, XR);
    gemm_proj<2><<<dim3(64, 4, 8), 256, 0, stream>>>(
        t_w, t_b, x, XR, nullptr, out);
    k6_bnstats <<<dim3(512), 256, 0, stream>>>(out, gamma, beta, bnp);
    k7_final <<<dim3(33554432 / 1024), 256, 0, stream>>>(x, bnp, out);
}

// Round 6
// 712.749 us; speedup vs baseline: 1.4318x; 1.3908x over previous
//
#include <hip/hip_runtime.h>
#include <math.h>

// SA_Layer2 — ROUND 11: projections to m97-structure (global_load_lds) GEMMs.
// r10 profile: gemm_proj 2x303us, MfmaUtil 4.4%, VALUBusy 14.6%, HBM 10% —
// issue-bound staging (32 scalar x-loads + 64 f2b per thread per K-step).
//  1) prep_x: x [b][c][hw] fp32 -> XT [b][hw][c] bf16 ONCE (LDS transpose).
//  2) wconv: weights fp32 -> bf16 [m][k] once.
//  3) gemm_proj K-loop: 8 global_load_lds(16B)/wave, linear LDS dest +
//     inverse-swizzled per-lane GLOBAL source; frag ds_read_b128 keeps the
//     XOR swizzle (conflict-free, r10-verified).  No converts in the loop.
//  4) k4 epilogue: XRm = bf16(x) - x_r written IN PLACE into XT (reads are
//     the same coalesced addresses it writes).  MODE2 = pure bf16 GEMM on XT;
//     old XR buffer deleted.
//  5) ws footprint unchanged (151,261,184 B): wv/wt time-share the Qs slot,
//     wq+bnp live in the old lbuf gap.

typedef unsigned short u16;
typedef __attribute__((ext_vector_type(4))) float f32x4;
typedef __attribute__((ext_vector_type(8))) short s16x8;
typedef __attribute__((ext_vector_type(4))) u16  u16x4;

__device__ __forceinline__ float b2f(u16 u) {
    unsigned x = ((unsigned)u) << 16;
    float f;
    __builtin_memcpy(&f, &x, 4);
    return f;
}
__device__ __forceinline__ u16 f2b(float f) {
    unsigned x;
    __builtin_memcpy(&x, &f, 4);
    unsigned r = (x + 0x7fffu + ((x >> 16) & 1u)) >> 16;  // round-nearest-even
    return (u16)r;
}
__device__ __forceinline__ float expc(float e) {
    return expf(fminf(e, 80.0f));
}
__device__ __forceinline__ void gload16(const void* g, void* l) {
    __builtin_amdgcn_global_load_lds(
        (const __attribute__((address_space(1))) unsigned int*)g,
        (__attribute__((address_space(3))) unsigned int*)l, 16, 0, 0);
}

// ---------------------------------------------------------------------------
// prep_x: x [b][c][hw] fp32 -> XT [b][hw][c] bf16.  64c x 64hw tile per block.
// grid = (128 hw-tiles, 8 c-tiles, 8 b), block = 256.
// ---------------------------------------------------------------------------
__global__ __launch_bounds__(256) void prep_x(
    const float* __restrict__ x, u16* __restrict__ XT)
{
    const int tid = threadIdx.x;
    const int hw0 = blockIdx.x * 64;
    const int c0  = blockIdx.y * 64;
    const int b   = blockIdx.z;

    __shared__ __align__(16) u16 lt[64 * 72];   // [hw][c], stride 72 (16B-aligned rows)

    const int hwl = tid & 63;
    const int cb  = (tid >> 6) * 16;
#pragma unroll
    for (int r = 0; r < 16; ++r) {
        const int cl = cb + r;
        const float v = x[((size_t)(b * 512 + c0 + cl)) * 8192 + hw0 + hwl];
        lt[hwl * 72 + cl] = f2b(v);
    }
    __syncthreads();
#pragma unroll
    for (int p = 0; p < 2; ++p) {
        const int g   = tid + p * 256;          // 512 granules = 64hw x 8cg
        const int hwl2 = g >> 3;
        const int cg   = g & 7;
        const s16x8 v = *(const s16x8*)(lt + hwl2 * 72 + cg * 8);
        *(s16x8*)(XT + ((size_t)(b * 8192 + hw0 + hwl2)) * 512 + c0 + cg * 8) = v;
    }
}

// ---------------------------------------------------------------------------
// wconv: fp32 -> bf16, 8 elems/thread.  total elems = grid * 2048.
// ---------------------------------------------------------------------------
__global__ __launch_bounds__(256) void wconv(
    const float* __restrict__ w, u16* __restrict__ wb)
{
    const size_t i = ((size_t)blockIdx.x * 256 + threadIdx.x) * 8;
    const f32x4 u0 = *(const f32x4*)(w + i);
    const f32x4 u1 = *(const f32x4*)(w + i + 4);
    s16x8 r;
#pragma unroll
    for (int j = 0; j < 4; ++j) {
        r[j]     = (short)f2b(u0[j]);
        r[4 + j] = (short)f2b(u1[j]);
    }
    *(s16x8*)(wb + i) = r;
}

// ---------------------------------------------------------------------------
// MFMA projection GEMM (m97 structure).  grid = (64, M/128, 8), block = 256.
//  A = Wb bf16 [M][512] (k-contig), B = Bm bf16 [b][8192][512] (k-contig).
//  MODE 0: out Qs [s][h][128];  MODE 1: out Vt [s][c][h] (+v_b);
//  MODE 2: out T fp32 x-layout (+t_b).
// ---------------------------------------------------------------------------
template<int MODE>
__global__ __launch_bounds__(256) void gemm_proj(
    const u16* __restrict__ Wb, const float* __restrict__ bias,
    const u16* __restrict__ Bm,
    u16* __restrict__ outb, float* __restrict__ outf)
{
    const int tid  = threadIdx.x;
    const int b    = blockIdx.z;
    const int n0   = blockIdx.x * 128;
    const int m0   = blockIdx.y * 128;
    const int wv   = tid >> 6;
    const int lane = tid & 63;
    const int lr   = lane & 15;
    const int lg   = lane >> 4;
    const int wm   = (wv & 1) * 64;
    const int wn   = (wv >> 1) * 64;

    __shared__ __align__(16) short lA[128 * 64];   // linear; swizzle via source
    __shared__ __align__(16) short lB[128 * 64];

    f32x4 acc[4][4];
    const f32x4 zero = {0.f, 0.f, 0.f, 0.f};
#pragma unroll
    for (int i = 0; i < 4; ++i)
#pragma unroll
        for (int j = 0; j < 4; ++j) acc[i][j] = zero;

    const u16* Bb = Bm + (size_t)b * 8192 * 512;

    for (int ks = 0; ks < 8; ++ks) {
        const int k0 = ks * 64;
        __syncthreads();   // prior compute done reading LDS
        // stage A+B: 1KB chunks; LDS dest linear, global granule inverse-swz
#pragma unroll
        for (int q = 0; q < 4; ++q) {
            const int ch = wv * 4 + q;
            const int gi = ch * 64 + lane;
            const int m  = gi >> 3;
            const int kg = (gi & 7) ^ (m & 7);
            gload16(Wb + (size_t)(m0 + m) * 512 + k0 + kg * 8, lA + ch * 512);
        }
#pragma unroll
        for (int q = 0; q < 4; ++q) {
            const int ch = wv * 4 + q;
            const int gi = ch * 64 + lane;
            const int n  = gi >> 3;
            const int kg = (gi & 7) ^ (n & 7);
            gload16(Bb + (size_t)(n0 + n) * 512 + k0 + kg * 8, lB + ch * 512);
        }
        __syncthreads();   // compiler drains vmcnt(0) before this barrier
#pragma unroll
        for (int kk = 0; kk < 2; ++kk) {
            const int g = kk * 4 + lg;
            s16x8 af[4], bf[4];
#pragma unroll
            for (int f = 0; f < 4; ++f) {
                const int r = wm + f * 16 + lr;
                af[f] = *(const s16x8*)(lA + r * 64 + ((g ^ (r & 7)) << 3));
            }
#pragma unroll
            for (int f = 0; f < 4; ++f) {
                const int r = wn + f * 16 + lr;
                bf[f] = *(const s16x8*)(lB + r * 64 + ((g ^ (r & 7)) << 3));
            }
#pragma unroll
            for (int fm = 0; fm < 4; ++fm)
#pragma unroll
                for (int fn = 0; fn < 4; ++fn)
                    acc[fm][fn] = __builtin_amdgcn_mfma_f32_16x16x32_bf16(
                        af[fm], bf[fn], acc[fm][fn], 0, 0, 0);
        }
    }

#pragma unroll
    for (int fm = 0; fm < 4; ++fm) {
        const int m = m0 + wm + fm * 16 + lg * 4;
#pragma unroll
        for (int fn = 0; fn < 4; ++fn) {
            const int n = n0 + wn + fn * 16 + lr;
            if (MODE == 0) {
                const size_t base =
                    ((size_t)((b * 8 + (n & 7)) * 1024 + (n >> 3))) * 128 + m;
                u16x4 o;
#pragma unroll
                for (int r = 0; r < 4; ++r) o[r] = f2b(acc[fm][fn][r]);
                *(u16x4*)(outb + base) = o;
            } else if (MODE == 1) {
                // Vt [s][c][h]: c = m+r, h = n>>3, s = b*8 + (n&7)
                const size_t base =
                    ((size_t)((b * 8 + (n & 7)) * 512 + m)) * 1024 + (n >> 3);
#pragma unroll
                for (int r = 0; r < 4; ++r)
                    outb[base + (size_t)r * 1024] =
                        f2b(acc[fm][fn][r] + bias[m + r]);
            } else {
#pragma unroll
                for (int r = 0; r < 4; ++r)
                    outf[((size_t)(b * 512 + m + r)) * 8192 + n] =
                        acc[fm][fn][r] + bias[m + r];
            }
        }
    }
}

// ---------------------------------------------------------------------------
// k4_fused: attention, all-MFMA (r10 core).  Epilogue now writes
// XT[b][hw][c] in place: XT = bf16(x) - x_r  (input for MODE2).
// grid = 2048 (XCD-swizzled), block = 256 (4 waves).
// ---------------------------------------------------------------------------
__global__ __launch_bounds__(256) void k4_fused(
    const u16* __restrict__ Qs, const u16* __restrict__ Vt, u16* __restrict__ XT)
{
    const int orig = blockIdx.x;
    const int swz  = (orig & 7) * 256 + (orig >> 3);   // nwg=2048, bijective
    const int s    = swz >> 5;
    const int jt   = swz & 31;

    const int tid  = threadIdx.x;
    const int b    = s >> 3, wimg = s & 7;
    const int j0   = jt * 32;
    const int w    = tid >> 6;
    const int lane = tid & 63;
    const int l15  = lane & 15;
    const int lg   = lane >> 4;
    const int jsub = w & 1;
    const int ih   = w >> 1;

    __shared__ __align__(16) short Vl[512 * 40];   // [c][i], pad 32->40
    __shared__ __align__(16) short Pt[32 * 40];    // [j][i]
    __shared__ float csum_lds[2][32];
    __shared__ float rls_lds[32];

    const long qrow = (long)s * 1024;
    const u16* vslice = Vt + (size_t)s * 512 * 1024;

    s16x8 qj[4];
    {
        const int j = j0 + jsub * 16 + l15;
#pragma unroll
        for (int kk = 0; kk < 4; ++kk)
            qj[kk] = *(const s16x8*)(Qs + (qrow + j) * 128 + (kk * 4 + lg) * 8);
    }

    f32x4 acc[16];
    const f32x4 zero = {0.f, 0.f, 0.f, 0.f};
#pragma unroll
    for (int f = 0; f < 16; ++f) acc[f] = zero;
    float csum = 0.f;

    const int sc  = tid >> 2;
    const int sig = tid & 3;

    s16x8 vS[8], qS[4];

    auto vload = [&](int it2) {
        const int ib = it2 * 32 + sig * 8;
#pragma unroll
        for (int q = 0; q < 8; ++q)
            vS[q] = *(const s16x8*)(vslice + (size_t)(sc + q * 64) * 1024 + ib);
    };
    auto qload = [&](int it2) {
        const int irow = it2 * 32 + ih * 16 + l15;
#pragma unroll
        for (int kk = 0; kk < 4; ++kk)
            qS[kk] = *(const s16x8*)(Qs + (qrow + irow) * 128 + (kk * 4 + lg) * 8);
    };

    vload(0);
    qload(0);

    for (int it = 0; it < 32; ++it) {
        __syncthreads();   // prev PV done reading Vl & Pt

#pragma unroll
        for (int q = 0; q < 8; ++q)
            *(s16x8*)(Vl + (sc + q * 64) * 40 + sig * 8) = vS[q];
        if (it < 31) vload(it + 1);

        f32x4 e = zero;
#pragma unroll
        for (int kk = 0; kk < 4; ++kk)
            e = __builtin_amdgcn_mfma_f32_16x16x32_bf16(qS[kk], qj[kk], e, 0, 0, 0);
        if (it < 31) qload(it + 1);

        u16x4 p4;
#pragma unroll
        for (int r = 0; r < 4; ++r) {
            const float pe = expc(e[r]);
            csum += pe;
            p4[r] = f2b(pe);
        }
        *(u16x4*)(Pt + (jsub * 16 + l15) * 40 + ih * 16 + lg * 4) = p4;

        __syncthreads();   // Vl + Pt visible

        const s16x8 af = *(const s16x8*)(Pt + (jsub * 16 + l15) * 40 + lg * 8);
#pragma unroll
        for (int fc = 0; fc < 16; ++fc) {
            const s16x8 bf =
                *(const s16x8*)(Vl + (ih * 256 + fc * 16 + l15) * 40 + lg * 8);
            acc[fc] = __builtin_amdgcn_mfma_f32_16x16x32_bf16(
                af, bf, acc[fc], 0, 0, 0);
        }
    }

    __syncthreads();
    csum += __shfl_xor(csum, 16, 64);
    csum += __shfl_xor(csum, 32, 64);
    if (lane < 16) csum_lds[ih][jsub * 16 + lane] = csum;
    __syncthreads();
    if (tid < 32)
        rls_lds[tid] = 1.0f / ((1.0f + 1e-9f) * (csum_lds[0][tid] + csum_lds[1][tid]));
    __syncthreads();

    // epilogue: XT[b][hw][c] in-place RMW: XT = x - x_r (bf16)
    u16* xm = XT + (size_t)b * 8192 * 512;
#pragma unroll
    for (int f = 0; f < 16; ++f) {
        const int c = ih * 256 + f * 16 + l15;
#pragma unroll
        for (int r = 0; r < 4; ++r) {
            const int jl = jsub * 16 + 4 * lg + r;
            const size_t a = (size_t)((j0 + jl) * 8 + wimg) * 512 + c;
            const float xv = b2f(xm[a]);
            xm[a] = f2b(xv - acc[f][r] * rls_lds[jl]);
        }
    }
}

// ---------------------------------------------------------------------------
// K6: one block per channel; float4 loads; deterministic LDS reduction.
// ---------------------------------------------------------------------------
__global__ __launch_bounds__(256) void k6_bnstats(
    const float* T, const float* gamma, const float* beta, float* bnp)
{
    const int c   = blockIdx.x;
    const int tid = threadIdx.x;
    float s1 = 0.f, s2 = 0.f;
    for (int b = 0; b < 8; ++b) {
        const f32x4* p = (const f32x4*)(T + ((long)(b * 512 + c)) * 8192);
        for (int m = 0; m < 8; ++m) {
            const f32x4 f = p[m * 256 + tid];
#pragma unroll
            for (int j = 0; j < 4; ++j) { s1 += f[j]; s2 += f[j] * f[j]; }
        }
    }
    __shared__ float r1[256], r2[256];
    r1[tid] = s1; r2[tid] = s2;
    __syncthreads();
    for (int o = 128; o > 0; o >>= 1) {
        if (tid < o) { r1[tid] += r1[tid + o]; r2[tid] += r2[tid + o]; }
        __syncthreads();
    }
    if (tid == 0) {
        const float inv_n = 1.0f / 65536.0f;
        const float mean = r1[0] * inv_n;
        const float var  = r2[0] * inv_n - mean * mean;
        const float sc   = gamma[c] * rsqrtf(var + 1e-5f);
        bnp[c]       = sc;
        bnp[512 + c] = beta[c] - mean * sc;
    }
}

// ---------------------------------------------------------------------------
// K7: out = x + relu(T*scale + shift), in place, float4 vectorized.
// ---------------------------------------------------------------------------
__global__ __launch_bounds__(256) void k7_final(
    const float* x, const float* bnp, float* out)
{
    const long i = ((long)blockIdx.x * 256 + threadIdx.x) * 4;
    const int c = (int)((i >> 13) & 511);
    const float sc = bnp[c], sh = bnp[512 + c];
    f32x4 t  = *(const f32x4*)(out + i);
    f32x4 xv = *(const f32x4*)(x + i);
    f32x4 r;
#pragma unroll
    for (int j = 0; j < 4; ++j) {
        float v = t[j] * sc + sh;
        if (v < 0.f) v = 0.f;
        r[j] = xv[j] + v;
    }
    *(f32x4*)(out + i) = r;
}

extern "C" void kernel_launch(void* const* d_in, const int* in_sizes, int n_in,
                              void* d_out, int out_size, void* d_ws, size_t ws_size,
                              hipStream_t stream)
{
    const float* x     = (const float*)d_in[0];
    const float* qk_w  = (const float*)d_in[1];
    const float* v_w   = (const float*)d_in[2];
    const float* v_b   = (const float*)d_in[3];
    const float* t_w   = (const float*)d_in[4];
    const float* t_b   = (const float*)d_in[5];
    const float* gamma = (const float*)d_in[6];
    const float* beta  = (const float*)d_in[7];
    float* out = (float*)d_out;

    char* ws = (char*)d_ws;
    u16*   Qs  = (u16*)(ws);                    // 16 MiB  [64][1024][128]
    u16*   Vt  = (u16*)(ws + 16777216);         // 64 MiB  [64][512][1024]
    u16*   XT  = (u16*)(ws + 83886080);         // 64 MiB  [b][8192][512] bf16 (x, then x - x_r)
    u16*   wq  = (u16*)(ws + 150994944);        // 128 KiB (old lbuf gap)
    float* bnp = (float*)(ws + 151126016);      // 4 KiB   (old lbuf gap)
    u16*   wv  = (u16*)(ws);                    // 512 KiB, Qs slot pre-MODE0
    u16*   wt  = (u16*)(ws);                    // 512 KiB, Qs slot post-k4
    // footprint unchanged: max offset 151,261,184 B

    prep_x <<<dim3(128, 8, 8), 256, 0, stream>>>(x, XT);
    wconv  <<<dim3(128), 256, 0, stream>>>(v_w, wv);          // 262144 elems
    gemm_proj<1><<<dim3(64, 4, 8), 256, 0, stream>>>(wv, v_b, XT, Vt, nullptr);
    wconv  <<<dim3(32), 256, 0, stream>>>(qk_w, wq);          // 65536 elems
    gemm_proj<0><<<dim3(64, 1, 8), 256, 0, stream>>>(wq, nullptr, XT, Qs, nullptr);
    k4_fused <<<dim3(2048), 256, 0, stream>>>(Qs, Vt, XT);
    wconv  <<<dim3(128), 256, 0, stream>>>(t_w, wt);          // 262144 elems
    gemm_proj<2><<<dim3(64, 4, 8), 256, 0, stream>>>(wt, t_b, XT, nullptr, out);
    k6_bnstats <<<dim3(512), 256, 0, stream>>>(out, gamma, beta, bnp);
    k7_final <<<dim3(33554432 / 1024), 256, 0, stream>>>(x, bnp, out);
}